// Round 1
// 438.807 us; speedup vs baseline: 1.3251x; 1.3251x over previous
//
#include <hip/hip_runtime.h>
#include <stdint.h>

// Problem constants: x[8192,4096] f32, w[4096,4096] f32, bias[4096] f32.
#define NROW 8192
#define KDIM 4096
#define NOUT 4096

typedef __attribute__((ext_vector_type(4))) int i32x4;

// ---------------------------------------------------------------------------
// Kernel 1: sign-binarize f32 -> i8 {-1,+1} (as bytes 0xFF / 0x01), 4 per u32.
// Each thread: one float4 load (16B) -> one u32 store. Pure BW-bound.
// Reference: sign(x>=0)=+1, so only x<0 -> -1.
// ---------------------------------------------------------------------------
__global__ __launch_bounds__(256)
void bin_i8_kernel(const float* __restrict__ x, uint32_t* __restrict__ q, int n4) {
    int i = blockIdx.x * blockDim.x + threadIdx.x;
    const int stride = gridDim.x * blockDim.x;
    for (; i < n4; i += stride) {
        float4 v = ((const float4*)x)[i];
        uint32_t b0 = (v.x < 0.0f) ? 0xFFu : 0x01u;
        uint32_t b1 = (v.y < 0.0f) ? 0xFFu : 0x01u;
        uint32_t b2 = (v.z < 0.0f) ? 0xFFu : 0x01u;
        uint32_t b3 = (v.w < 0.0f) ? 0xFFu : 0x01u;
        q[i] = b0 | (b1 << 8) | (b2 << 16) | (b3 << 24);
    }
}

// ---------------------------------------------------------------------------
// Kernel 2: i8 MFMA GEMM.  C[n,o] = sum_k xq[n,k]*wq[o,k] + bias[o]
// (both operands +-1 i8; i32 accumulate is exact; matches fp32 ref exactly).
//
// 128x128 tile, 256 threads = 4 waves (2x2), each wave owns 64x64 out =
// 4x4 fragments of mfma_i32_16x16x64_i8. BK=64 i8 per K-step, 64 K-steps.
// Double-buffered LDS (2 x (8KB A + 8KB B)), staged via global_load_lds
// width=16 (linear dest = wave-uniform base + lane*16). Stage of tile t+1
// is issued BEFORE compute of tile t; the vmcnt drain at the next barrier
// completes it (loads in flight across compute).
// LDS rows are 64B -> fragment ds_read_b128s spread uniformly over the
// 8 16B-slots per 128B bank window: no swizzle needed.
// ---------------------------------------------------------------------------
#define BM 128
#define BN 128
#define BK 64

__device__ __forceinline__ void gload_lds16(const void* g, void* l) {
    __builtin_amdgcn_global_load_lds(
        (const __attribute__((address_space(1))) uint32_t*)g,
        (__attribute__((address_space(3))) uint32_t*)l, 16, 0, 0);
}

__global__ __launch_bounds__(256)
void i8_mfma_gemm(const uint8_t* __restrict__ xq, const uint8_t* __restrict__ wq,
                  const float* __restrict__ bias, float* __restrict__ out) {
    __shared__ __align__(16) uint8_t As[2][BM][BK];   // 16 KB
    __shared__ __align__(16) uint8_t Bs[2][BN][BK];   // 16 KB

    const int tid  = threadIdx.x;
    const int wid  = tid >> 6;        // wave 0..3
    const int lane = tid & 63;
    const int wr   = wid >> 1;        // wave row 0..1 (64-row slab)
    const int wc   = wid & 1;         // wave col 0..1 (64-col slab)
    const int row0 = blockIdx.y * BM;
    const int col0 = blockIdx.x * BN;

    // Staging assignment: tile = 128 rows x 64B = 512 chunks of 16B.
    // Wave w, round r covers chunks [r*256 + w*64, +64), lane-contiguous.
    const int c0 = wid * 64 + lane;        // round 0 chunk
    const int c1 = 256 + wid * 64 + lane;  // round 1 chunk
    const int r0A = c0 >> 2, k0A = (c0 & 3) * 16;
    const int r1A = c1 >> 2, k1A = (c1 & 3) * 16;

    const uint8_t* gA0 = xq + (size_t)(row0 + r0A) * KDIM + k0A;
    const uint8_t* gA1 = xq + (size_t)(row0 + r1A) * KDIM + k1A;
    const uint8_t* gB0 = wq + (size_t)(col0 + r0A) * KDIM + k0A;
    const uint8_t* gB1 = wq + (size_t)(col0 + r1A) * KDIM + k1A;

    i32x4 acc[4][4];
#pragma unroll
    for (int m = 0; m < 4; ++m)
#pragma unroll
        for (int n = 0; n < 4; ++n) acc[m][n] = (i32x4){0, 0, 0, 0};

    const int g  = lane >> 4;   // k-chunk group 0..3 (k = g*16 .. g*16+15)
    const int lr = lane & 15;   // row (A) / col (B) within 16

    // Prologue: stage tile 0 into buffer 0.
    {
        uint8_t* la = &As[0][0][0];
        uint8_t* lb = &Bs[0][0][0];
        gload_lds16(gA0, la + c0 * 16);
        gload_lds16(gA1, la + c1 * 16);
        gload_lds16(gB0, lb + c0 * 16);
        gload_lds16(gB1, lb + c1 * 16);
    }

    int cur = 0;
    for (int kb = 0; kb < KDIM; kb += BK) {
        // Drains vmcnt (stage of buf[cur] complete) and orders prev compute
        // before we overwrite buf[cur^1].
        __syncthreads();

        if (kb + BK < KDIM) {
            const int nxt = cur ^ 1;
            uint8_t* la = &As[nxt][0][0];
            uint8_t* lb = &Bs[nxt][0][0];
            const int ko = kb + BK;
            gload_lds16(gA0 + ko, la + c0 * 16);
            gload_lds16(gA1 + ko, la + c1 * 16);
            gload_lds16(gB0 + ko, lb + c0 * 16);
            gload_lds16(gB1 + ko, lb + c1 * 16);
        }

        i32x4 af[4], bf[4];
#pragma unroll
        for (int m = 0; m < 4; ++m)
            af[m] = *(const i32x4*)&As[cur][wr * 64 + m * 16 + lr][g * 16];
#pragma unroll
        for (int n = 0; n < 4; ++n)
            bf[n] = *(const i32x4*)&Bs[cur][wc * 64 + n * 16 + lr][g * 16];

#pragma unroll
        for (int m = 0; m < 4; ++m)
#pragma unroll
            for (int n = 0; n < 4; ++n)
                acc[m][n] = __builtin_amdgcn_mfma_i32_16x16x64_i8(
                    af[m], bf[n], acc[m][n], 0, 0, 0);

        cur ^= 1;
    }

    // Epilogue. C/D layout (16x16, dtype-independent): col = lane&15,
    // row = (lane>>4)*4 + reg.
#pragma unroll
    for (int n = 0; n < 4; ++n) {
        const int col = col0 + wc * 64 + n * 16 + lr;
        const float bv = bias[col];
#pragma unroll
        for (int m = 0; m < 4; ++m) {
            const int rbase = row0 + wr * 64 + m * 16 + g * 4;
#pragma unroll
            for (int r = 0; r < 4; ++r)
                out[(size_t)(rbase + r) * NOUT + col] = (float)acc[m][n][r] + bv;
        }
    }
}

// ---------------------------------------------------------------------------
extern "C" void kernel_launch(void* const* d_in, const int* in_sizes, int n_in,
                              void* d_out, int out_size, void* d_ws, size_t ws_size,
                              hipStream_t stream) {
    const float* x = (const float*)d_in[0];   // [8192, 4096]
    const float* w = (const float*)d_in[1];   // [4096, 4096]
    const float* b = (const float*)d_in[2];   // [4096]
    float* out = (float*)d_out;               // [8192, 4096]

    // Workspace: xq 32 MiB + wq 16 MiB = 48 MiB of i8 (+-1).
    uint8_t* xq = (uint8_t*)d_ws;
    uint8_t* wq = xq + (size_t)NROW * KDIM;
    (void)ws_size;

    bin_i8_kernel<<<2048, 256, 0, stream>>>(x, (uint32_t*)xq, NROW * KDIM / 4);
    bin_i8_kernel<<<1024, 256, 0, stream>>>(w, (uint32_t*)wq, NOUT * KDIM / 4);

    dim3 grid(NOUT / BN, NROW / BM);
    i8_mfma_gemm<<<grid, 256, 0, stream>>>(xq, wq, b, out);
}

// Round 2
// 434.065 us; speedup vs baseline: 1.3396x; 1.0109x over previous
//
#include <hip/hip_runtime.h>
#include <stdint.h>

// Problem constants: x[8192,4096] f32, w[4096,4096] f32, bias[4096] f32.
#define NROW 8192
#define KDIM 4096
#define NOUT 4096

typedef __attribute__((ext_vector_type(4))) int i32x4;

// ---------------------------------------------------------------------------
// Kernel 1: sign-binarize f32 -> i8 {-1,+1} (bytes 0x01 / 0xFF), 4 per u32.
// Fused: handles x then w in one grid-stride index space (one launch).
// Each thread-iter: one float4 load (16B) -> one u32 store. Pure BW-bound.
// Reference sign: x >= 0 -> +1, x < 0 -> -1.
// ---------------------------------------------------------------------------
__global__ __launch_bounds__(256)
void bin_i8_fused(const float* __restrict__ x, const float* __restrict__ w,
                  uint32_t* __restrict__ xq, uint32_t* __restrict__ wq,
                  int n4x, int n4tot) {
    int i = blockIdx.x * blockDim.x + threadIdx.x;
    const int stride = gridDim.x * blockDim.x;
    for (; i < n4tot; i += stride) {
        const float4* src;
        uint32_t* dst;
        int j;
        if (i < n4x) { src = (const float4*)x; dst = xq; j = i; }
        else         { src = (const float4*)w; dst = wq; j = i - n4x; }
        float4 v = src[j];
        uint32_t b0 = (v.x < 0.0f) ? 0xFFu : 0x01u;
        uint32_t b1 = (v.y < 0.0f) ? 0xFFu : 0x01u;
        uint32_t b2 = (v.z < 0.0f) ? 0xFFu : 0x01u;
        uint32_t b3 = (v.w < 0.0f) ? 0xFFu : 0x01u;
        dst[j] = b0 | (b1 << 8) | (b2 << 16) | (b3 << 24);
    }
}

// ---------------------------------------------------------------------------
// Kernel 2: i8 MFMA GEMM.  C[n,o] = sum_k xq[n,k]*wq[o,k] + bias[o]
//
// 128x128 tile, 4 waves (2x2), each wave 64x64 out = 4x4 frags of
// mfma_i32_16x16x64_i8. BK=64 i8, double-buffered LDS via global_load_lds
// width=16 (linear dest).
//
// LDS bank-conflict fix (rule #21: both-sides-or-neither):
//   Unswizzled, a fragment ds_read_b128 has 16 lanes at byte = row*64+g*16
//   over 16 consecutive rows -> addr%128 takes 2 values -> 8-way conflict
//   (measured 1.68e7 SQ_LDS_BANK_CONFLICT).
//   Swizzle: LDS slot s_l holds global k-slot s_g = s_l ^ ((row>>1)&3).
//   - write side: LDS dest stays LINEAR (gload_lds requirement); the GLOBAL
//     source k-offset is pre-swizzled per chunk.
//   - read side: slot = g ^ ((lr>>1)&3) (per-lane constant).
//   Each wave's b128 read then covers every 16B slot of a contiguous 1024B
//   LDS region exactly once -> conflict-free by construction.
// ---------------------------------------------------------------------------
#define BM 128
#define BN 128
#define BK 64

__device__ __forceinline__ void gload_lds16(const void* g, void* l) {
    __builtin_amdgcn_global_load_lds(
        (const __attribute__((address_space(1))) uint32_t*)g,
        (__attribute__((address_space(3))) uint32_t*)l, 16, 0, 0);
}

__global__ __launch_bounds__(256)
void i8_mfma_gemm(const uint8_t* __restrict__ xq, const uint8_t* __restrict__ wq,
                  const float* __restrict__ bias, float* __restrict__ out) {
    __shared__ __align__(16) uint8_t As[2][BM][BK];   // 16 KB
    __shared__ __align__(16) uint8_t Bs[2][BN][BK];   // 16 KB

    const int tid  = threadIdx.x;
    const int wid  = tid >> 6;        // wave 0..3
    const int lane = tid & 63;
    const int wr   = wid >> 1;        // wave row 0..1 (64-row slab)
    const int wc   = wid & 1;         // wave col 0..1 (64-col slab)
    const int row0 = blockIdx.y * BM;
    const int col0 = blockIdx.x * BN;

    // Staging: tile = 128 rows x 64B = 512 chunks of 16B. Wave w, round r
    // covers chunks [r*256 + w*64, +64) -> LDS dest linear in chunk index.
    // Global k-offset per chunk is the inverse swizzle:
    //   row = c>>2, s_l = c&3, s_g = s_l ^ ((row>>1)&3) = (c&3) ^ ((c>>3)&3).
    const int c0 = wid * 64 + lane;
    const int c1 = 256 + wid * 64 + lane;
    const int r0 = c0 >> 2, k0 = ((c0 & 3) ^ ((c0 >> 3) & 3)) * 16;
    const int r1 = c1 >> 2, k1 = ((c1 & 3) ^ ((c1 >> 3) & 3)) * 16;

    const uint8_t* gA0 = xq + (size_t)(row0 + r0) * KDIM + k0;
    const uint8_t* gA1 = xq + (size_t)(row0 + r1) * KDIM + k1;
    const uint8_t* gB0 = wq + (size_t)(col0 + r0) * KDIM + k0;
    const uint8_t* gB1 = wq + (size_t)(col0 + r1) * KDIM + k1;

    i32x4 acc[4][4];
#pragma unroll
    for (int m = 0; m < 4; ++m)
#pragma unroll
        for (int n = 0; n < 4; ++n) acc[m][n] = (i32x4){0, 0, 0, 0};

    const int g    = lane >> 4;   // k-chunk group 0..3
    const int lr   = lane & 15;   // row (A) / col (B) within fragment
    const int swzk = (g ^ ((lr >> 1) & 3)) * 16;   // swizzled k-slot byte

    // Prologue: stage tile 0 into buffer 0.
    {
        uint8_t* la = &As[0][0][0];
        uint8_t* lb = &Bs[0][0][0];
        gload_lds16(gA0, la + c0 * 16);
        gload_lds16(gA1, la + c1 * 16);
        gload_lds16(gB0, lb + c0 * 16);
        gload_lds16(gB1, lb + c1 * 16);
    }

    int cur = 0;
    for (int kb = 0; kb < KDIM; kb += BK) {
        // Drains vmcnt (stage of buf[cur] complete) and orders prev compute
        // before buf[cur^1] is overwritten.
        __syncthreads();

        if (kb + BK < KDIM) {
            const int nxt = cur ^ 1;
            uint8_t* la = &As[nxt][0][0];
            uint8_t* lb = &Bs[nxt][0][0];
            const int ko = kb + BK;
            gload_lds16(gA0 + ko, la + c0 * 16);
            gload_lds16(gA1 + ko, la + c1 * 16);
            gload_lds16(gB0 + ko, lb + c0 * 16);
            gload_lds16(gB1 + ko, lb + c1 * 16);
        }

        i32x4 af[4], bf[4];
#pragma unroll
        for (int m = 0; m < 4; ++m)
            af[m] = *(const i32x4*)&As[cur][wr * 64 + m * 16 + lr][swzk];
#pragma unroll
        for (int n = 0; n < 4; ++n)
            bf[n] = *(const i32x4*)&Bs[cur][wc * 64 + n * 16 + lr][swzk];

#pragma unroll
        for (int m = 0; m < 4; ++m)
#pragma unroll
            for (int n = 0; n < 4; ++n)
                acc[m][n] = __builtin_amdgcn_mfma_i32_16x16x64_i8(
                    af[m], bf[n], acc[m][n], 0, 0, 0);

        cur ^= 1;
    }

    // Epilogue. C/D layout (16x16, dtype-independent): col = lane&15,
    // row = (lane>>4)*4 + reg.
#pragma unroll
    for (int n = 0; n < 4; ++n) {
        const int col = col0 + wc * 64 + n * 16 + lr;
        const float bv = bias[col];
#pragma unroll
        for (int m = 0; m < 4; ++m) {
            const int rbase = row0 + wr * 64 + m * 16 + g * 4;
#pragma unroll
            for (int r = 0; r < 4; ++r)
                out[(size_t)(rbase + r) * NOUT + col] = (float)acc[m][n][r] + bv;
        }
    }
}

// ---------------------------------------------------------------------------
extern "C" void kernel_launch(void* const* d_in, const int* in_sizes, int n_in,
                              void* d_out, int out_size, void* d_ws, size_t ws_size,
                              hipStream_t stream) {
    const float* x = (const float*)d_in[0];   // [8192, 4096]
    const float* w = (const float*)d_in[1];   // [4096, 4096]
    const float* b = (const float*)d_in[2];   // [4096]
    float* out = (float*)d_out;               // [8192, 4096]

    // Workspace: xq 32 MiB + wq 16 MiB = 48 MiB of i8 (+-1).
    uint8_t* xq = (uint8_t*)d_ws;
    uint8_t* wq = xq + (size_t)NROW * KDIM;
    (void)ws_size;

    const int n4x = NROW * KDIM / 4;
    const int n4t = n4x + NOUT * KDIM / 4;
    bin_i8_fused<<<3072, 256, 0, stream>>>(x, w, (uint32_t*)xq, (uint32_t*)wq,
                                           n4x, n4t);

    dim3 grid(NOUT / BN, NROW / BM);
    i8_mfma_gemm<<<grid, 256, 0, stream>>>(xq, wq, b, out);
}

// Round 3
// 432.103 us; speedup vs baseline: 1.3456x; 1.0045x over previous
//
#include <hip/hip_runtime.h>
#include <stdint.h>

// Problem constants: x[8192,4096] f32, w[4096,4096] f32, bias[4096] f32.
#define NROW 8192
#define KDIM 4096
#define NOUT 4096

typedef __attribute__((ext_vector_type(4))) int i32x4;

// ---------------------------------------------------------------------------
// Kernel 1: sign-binarize f32 -> i8 {-1,+1} (bytes 0x01 / 0xFF), 4 per u32.
// One fused launch for x and w. float4 load -> u32 store, BW-bound.
// ---------------------------------------------------------------------------
__global__ __launch_bounds__(256)
void bin_i8_fused(const float* __restrict__ x, const float* __restrict__ w,
                  uint32_t* __restrict__ xq, uint32_t* __restrict__ wq,
                  int n4x, int n4tot) {
    int i = blockIdx.x * blockDim.x + threadIdx.x;
    const int stride = gridDim.x * blockDim.x;
    for (; i < n4tot; i += stride) {
        const float4* src;
        uint32_t* dst;
        int j;
        if (i < n4x) { src = (const float4*)x; dst = xq; j = i; }
        else         { src = (const float4*)w; dst = wq; j = i - n4x; }
        float4 v = src[j];
        uint32_t b0 = (v.x < 0.0f) ? 0xFFu : 0x01u;
        uint32_t b1 = (v.y < 0.0f) ? 0xFFu : 0x01u;
        uint32_t b2 = (v.z < 0.0f) ? 0xFFu : 0x01u;
        uint32_t b3 = (v.w < 0.0f) ? 0xFFu : 0x01u;
        dst[j] = b0 | (b1 << 8) | (b2 << 16) | (b3 << 24);
    }
}

// ---------------------------------------------------------------------------
// Kernel 2: i8 MFMA GEMM, 8-phase counted-vmcnt schedule (T3+T4+T5).
//   C[n,o] = sum_k xq[n,k]*wq[o,k] + bias[o]   (exact i32 accumulate)
//
// Geometry: 256x256 tile, 512 threads = 8 waves (2Mx4N), per-wave 128x64 out
// = 8x4 frags of mfma_i32_16x16x64_i8. K-tile = 128 bytes, staged as 4
// half-tiles of 16KB (A/B x k-half). LDS [2dbuf][2khalf][256][64] = 128 KiB.
//
// Schedule per K-tile t (reads dbuf d=t&1, stages tile t+1 into dbuf d^1):
//   phase1 (mh0,ks0): ds_read a0[4]+b0[4]; STAGE A-kh0(t+1); bar; MFMA16; bar
//   phase2 (mh1,ks0): ds_read a1[4];       STAGE B-kh0(t+1); vmcnt(4); bar;
//                     MFMA16; bar
//   phase3 (mh0,ks1): ds_read a0[4]+b1[4]; STAGE A-kh1(t+1); bar; MFMA16; bar
//   phase4 (mh1,ks1): ds_read a1[4];       STAGE B-kh1(t+1); vmcnt(4); bar;
//                     MFMA16; bar
// vmcnt accounting (8 loads/thread/tile, issue order A0,B0,A1,B1):
//   wait at p2 retires the 4 oldest = prev tile's A1,B1 -> ready for p3;
//   wait at p4 retires this tile's A0,B0 -> ready for next p1.
// vmcnt never drains to 0 in the loop: loads stay in flight across barriers.
// Raw s_barrier (no counter drain); asm waits carry "memory" so the compiler
// cannot hoist the dependent ds_reads above them.
//
// Bank conflicts: both-sides XOR swizzle (verified 0 conflicts in r2).
// LDS slot s_l of row r holds global k-chunk s_g = s_l ^ (r&3); linear
// gload_lds dest + pre-swizzled global source; read slot = g ^ (lr&3).
// Each wave's ds_read_b128 covers a contiguous 1024B region exactly once.
// ---------------------------------------------------------------------------
#define BM 256
#define BN 256
#define BKB 128
#define NT (KDIM / BKB)   // 32

__device__ __forceinline__ void gload_lds16(const void* g, void* l) {
    __builtin_amdgcn_global_load_lds(
        (const __attribute__((address_space(1))) uint32_t*)g,
        (__attribute__((address_space(3))) uint32_t*)l, 16, 0, 0);
}

__global__ __launch_bounds__(512, 2)
void i8_mfma_gemm(const uint8_t* __restrict__ xq, const uint8_t* __restrict__ wq,
                  const float* __restrict__ bias, float* __restrict__ out) {
    __shared__ __align__(16) uint8_t As[2][2][256][64];   // 64 KiB
    __shared__ __align__(16) uint8_t Bs[2][2][256][64];   // 64 KiB

    const int tid  = threadIdx.x;
    const int wid  = tid >> 6;        // 0..7
    const int lane = tid & 63;
    const int wr   = wid >> 2;        // 0..1 : 128-row slab
    const int wc   = wid & 3;         // 0..3 : 64-col slab
    const int lr   = lane & 15;
    const int g    = lane >> 4;       // k-chunk 0..3 within 64B k-half
    const int row0 = blockIdx.y * BM;
    const int col0 = blockIdx.x * BN;

    // Staging: half-tile = 256 rows x 64B = 1024 chunks of 16B; 2 per thread.
    // LDS dest linear in chunk index; global k-slot pre-swizzled (inverse).
    const int c0 = wid * 64 + lane;   // 0..511
    const int c1 = 512 + c0;          // 512..1023
    const int r0 = c0 >> 2, s0 = ((c0 & 3) ^ (r0 & 3)) * 16;
    const int r1 = c1 >> 2, s1 = ((c1 & 3) ^ (r1 & 3)) * 16;

    const uint8_t* gA0 = xq + (size_t)(row0 + r0) * KDIM + s0;
    const uint8_t* gA1 = xq + (size_t)(row0 + r1) * KDIM + s1;
    const uint8_t* gB0 = wq + (size_t)(col0 + r0) * KDIM + s0;
    const uint8_t* gB1 = wq + (size_t)(col0 + r1) * KDIM + s1;

    const int sread = (g ^ (lr & 3)) * 16;   // swizzled read slot (bytes)
    const int ra = wr * 128 + lr;            // A fragment base row
    const int cb = wc * 64 + lr;             // B fragment base col

#define STAGE_A(sd, kh, ko) do {                                  \
        uint8_t* _l = &As[sd][kh][0][0];                          \
        gload_lds16(gA0 + (ko) + (kh) * 64, _l + c0 * 16);        \
        gload_lds16(gA1 + (ko) + (kh) * 64, _l + c1 * 16);        \
    } while (0)
#define STAGE_B(sd, kh, ko) do {                                  \
        uint8_t* _l = &Bs[sd][kh][0][0];                          \
        gload_lds16(gB0 + (ko) + (kh) * 64, _l + c0 * 16);        \
        gload_lds16(gB1 + (ko) + (kh) * 64, _l + c1 * 16);        \
    } while (0)

    i32x4 acc[8][4];
#pragma unroll
    for (int m = 0; m < 8; ++m)
#pragma unroll
        for (int n = 0; n < 4; ++n) acc[m][n] = (i32x4){0, 0, 0, 0};

    // Prologue: stage tile 0 (issue order A0,B0,A1,B1 = wait order).
    STAGE_A(0, 0, 0);
    STAGE_B(0, 0, 0);
    STAGE_A(0, 1, 0);
    STAGE_B(0, 1, 0);
    asm volatile("s_waitcnt vmcnt(4)" ::: "memory");   // A-kh0,B-kh0 landed
    __builtin_amdgcn_s_barrier();

#pragma unroll 1
    for (int t = 0; t < NT; ++t) {
        const int d  = t & 1;
        const int sd = d ^ 1;
        // Last tile re-stages its own sources (keeps vmcnt counts uniform;
        // lands in the dbuf that is no longer read -> harmless).
        const int ko = (t + 1 < NT ? t + 1 : t) * BKB;

        i32x4 a0[4], a1[4], b0[4], b1[4];

        // ---------------- phase 1: (mh=0, ks=0) ----------------
#pragma unroll
        for (int m = 0; m < 4; ++m)
            a0[m] = *(const i32x4*)&As[d][0][ra + m * 16][sread];
#pragma unroll
        for (int n = 0; n < 4; ++n)
            b0[n] = *(const i32x4*)&Bs[d][0][cb + n * 16][sread];
        STAGE_A(sd, 0, ko);
        __builtin_amdgcn_s_barrier();
        __builtin_amdgcn_s_setprio(1);
#pragma unroll
        for (int m = 0; m < 4; ++m)
#pragma unroll
            for (int n = 0; n < 4; ++n)
                acc[m][n] = __builtin_amdgcn_mfma_i32_16x16x64_i8(
                    a0[m], b0[n], acc[m][n], 0, 0, 0);
        __builtin_amdgcn_s_setprio(0);
        __builtin_amdgcn_s_barrier();

        // ---------------- phase 2: (mh=1, ks=0) ----------------
#pragma unroll
        for (int m = 0; m < 4; ++m)
            a1[m] = *(const i32x4*)&As[d][0][ra + 64 + m * 16][sread];
        STAGE_B(sd, 0, ko);
        asm volatile("s_waitcnt vmcnt(4)" ::: "memory");   // prev A1,B1 landed
        __builtin_amdgcn_s_barrier();
        __builtin_amdgcn_s_setprio(1);
#pragma unroll
        for (int m = 0; m < 4; ++m)
#pragma unroll
            for (int n = 0; n < 4; ++n)
                acc[4 + m][n] = __builtin_amdgcn_mfma_i32_16x16x64_i8(
                    a1[m], b0[n], acc[4 + m][n], 0, 0, 0);
        __builtin_amdgcn_s_setprio(0);
        __builtin_amdgcn_s_barrier();

        // ---------------- phase 3: (mh=0, ks=1) ----------------
#pragma unroll
        for (int m = 0; m < 4; ++m)
            a0[m] = *(const i32x4*)&As[d][1][ra + m * 16][sread];
#pragma unroll
        for (int n = 0; n < 4; ++n)
            b1[n] = *(const i32x4*)&Bs[d][1][cb + n * 16][sread];
        STAGE_A(sd, 1, ko);
        __builtin_amdgcn_s_barrier();
        __builtin_amdgcn_s_setprio(1);
#pragma unroll
        for (int m = 0; m < 4; ++m)
#pragma unroll
            for (int n = 0; n < 4; ++n)
                acc[m][n] = __builtin_amdgcn_mfma_i32_16x16x64_i8(
                    a0[m], b1[n], acc[m][n], 0, 0, 0);
        __builtin_amdgcn_s_setprio(0);
        __builtin_amdgcn_s_barrier();

        // ---------------- phase 4: (mh=1, ks=1) ----------------
#pragma unroll
        for (int m = 0; m < 4; ++m)
            a1[m] = *(const i32x4*)&As[d][1][ra + 64 + m * 16][sread];
        STAGE_B(sd, 1, ko);
        asm volatile("s_waitcnt vmcnt(4)" ::: "memory");   // this A0,B0 landed
        __builtin_amdgcn_s_barrier();
        __builtin_amdgcn_s_setprio(1);
#pragma unroll
        for (int m = 0; m < 4; ++m)
#pragma unroll
            for (int n = 0; n < 4; ++n)
                acc[4 + m][n] = __builtin_amdgcn_mfma_i32_16x16x64_i8(
                    a1[m], b1[n], acc[4 + m][n], 0, 0, 0);
        __builtin_amdgcn_s_setprio(0);
        __builtin_amdgcn_s_barrier();
    }
#undef STAGE_A
#undef STAGE_B

    // Epilogue. C/D layout (16x16): col = lane&15, row = (lane>>4)*4 + reg.
#pragma unroll
    for (int n = 0; n < 4; ++n) {
        const int col = col0 + wc * 64 + n * 16 + lr;
        const float bv = bias[col];
#pragma unroll
        for (int m = 0; m < 8; ++m) {
            const int rb = row0 + wr * 128 + m * 16 + g * 4;
#pragma unroll
            for (int r = 0; r < 4; ++r)
                out[(size_t)(rb + r) * NOUT + col] = (float)acc[m][n][r] + bv;
        }
    }
}

// ---------------------------------------------------------------------------
extern "C" void kernel_launch(void* const* d_in, const int* in_sizes, int n_in,
                              void* d_out, int out_size, void* d_ws, size_t ws_size,
                              hipStream_t stream) {
    const float* x = (const float*)d_in[0];   // [8192, 4096]
    const float* w = (const float*)d_in[1];   // [4096, 4096]
    const float* b = (const float*)d_in[2];   // [4096]
    float* out = (float*)d_out;               // [8192, 4096]

    // Workspace: xq 32 MiB + wq 16 MiB of i8 (+-1).
    uint8_t* xq = (uint8_t*)d_ws;
    uint8_t* wq = xq + (size_t)NROW * KDIM;
    (void)ws_size;

    const int n4x = NROW * KDIM / 4;
    const int n4t = n4x + NOUT * KDIM / 4;
    bin_i8_fused<<<3072, 256, 0, stream>>>(x, w, (uint32_t*)xq, (uint32_t*)wq,
                                           n4x, n4t);

    dim3 grid(NOUT / BN, NROW / BM);   // 16 x 32 = 512 blocks
    i8_mfma_gemm<<<grid, 512, 0, stream>>>(xq, wq, b, out);
}

// Round 4
// 422.749 us; speedup vs baseline: 1.3754x; 1.0221x over previous
//
#include <hip/hip_runtime.h>
#include <stdint.h>

// Problem constants: x[8192,4096] f32, w[4096,4096] f32, bias[4096] f32.
#define NROW 8192
#define KDIM 4096
#define NOUT 4096

typedef __attribute__((ext_vector_type(4))) int i32x4;

// ---------------------------------------------------------------------------
// Kernel 1: sign-binarize f32 -> i8 {-1,+1} (bytes 0x01 / 0xFF), 4 per u32.
// One fused launch for x and w. float4 load -> u32 store, BW-bound.
// ---------------------------------------------------------------------------
__global__ __launch_bounds__(256)
void bin_i8_fused(const float* __restrict__ x, const float* __restrict__ w,
                  uint32_t* __restrict__ xq, uint32_t* __restrict__ wq,
                  int n4x, int n4tot) {
    int i = blockIdx.x * blockDim.x + threadIdx.x;
    const int stride = gridDim.x * blockDim.x;
    for (; i < n4tot; i += stride) {
        const float4* src;
        uint32_t* dst;
        int j;
        if (i < n4x) { src = (const float4*)x; dst = xq; j = i; }
        else         { src = (const float4*)w; dst = wq; j = i - n4x; }
        float4 v = src[j];
        uint32_t b0 = (v.x < 0.0f) ? 0xFFu : 0x01u;
        uint32_t b1 = (v.y < 0.0f) ? 0xFFu : 0x01u;
        uint32_t b2 = (v.z < 0.0f) ? 0xFFu : 0x01u;
        uint32_t b3 = (v.w < 0.0f) ? 0xFFu : 0x01u;
        dst[j] = b0 | (b1 << 8) | (b2 << 16) | (b3 << 24);
    }
}

// ---------------------------------------------------------------------------
// Kernel 2: i8 MFMA GEMM, 8-phase counted-vmcnt schedule (T3+T4+T5).
//   C[n,o] = sum_k xq[n,k]*wq[o,k] + bias[o]   (exact i32 accumulate)
//
// Geometry: 256x256 tile, 512 threads = 8 waves (2Mx4N), per-wave 128x64 out
// = 8x4 frags of mfma_i32_16x16x64_i8. K-tile = 128 bytes, staged as 4
// half-tiles of 16KB (A/B x k-half). LDS [2dbuf][2khalf][256][64] = 128 KiB.
//
// Schedule per K-tile t (reads dbuf d=t&1, stages tile t+1 into dbuf d^1):
//   phase1 (mh0,ks0): ds_read a0[4]+b0[4]; STAGE A-kh0(t+1); bar; MFMA16; bar
//   phase2 (mh1,ks0): ds_read a1[4];       STAGE B-kh0(t+1); vmcnt(4); bar;
//                     MFMA16; bar
//   phase3 (mh0,ks1): ds_read a0[4]+b1[4]; STAGE A-kh1(t+1); bar; MFMA16; bar
//   phase4 (mh1,ks1): ds_read a1[4];       STAGE B-kh1(t+1); vmcnt(4); bar;
//                     MFMA16; bar
// vmcnt accounting (8 loads/thread/tile, issue order A0,B0,A1,B1):
//   wait at p2 retires the 4 oldest = prev tile's A1,B1 -> ready for p3;
//   wait at p4 retires this tile's A0,B0 -> ready for next p1.
// vmcnt never drains to 0 in the loop.
//
// Bank-conflict swizzle (round-2-verified variant, 0 conflicts measured):
//   LDS slot s_l of row r holds global k-chunk s_g = s_l ^ ((r>>1)&3);
//   linear gload_lds dest + pre-swizzled GLOBAL source; read slot =
//   g ^ ((lr>>1)&3). Bank check (per 16-lane read group g): bank-quad =
//   4*(lr&1) + (g ^ ((lr>>1)&3)); (lr&1, (lr>>1)&3) covers all 8 quads
//   exactly twice -> 2-way = free. (The round-3 variant g^(lr&3) collapsed
//   to 4 quads x 4 lanes -> 4-way conflict, measured 1.26e7.)
// ---------------------------------------------------------------------------
#define BM 256
#define BN 256
#define BKB 128
#define NT (KDIM / BKB)   // 32

__device__ __forceinline__ void gload_lds16(const void* g, void* l) {
    __builtin_amdgcn_global_load_lds(
        (const __attribute__((address_space(1))) uint32_t*)g,
        (__attribute__((address_space(3))) uint32_t*)l, 16, 0, 0);
}

__global__ __launch_bounds__(512, 2)
void i8_mfma_gemm(const uint8_t* __restrict__ xq, const uint8_t* __restrict__ wq,
                  const float* __restrict__ bias, float* __restrict__ out) {
    __shared__ __align__(16) uint8_t As[2][2][256][64];   // 64 KiB
    __shared__ __align__(16) uint8_t Bs[2][2][256][64];   // 64 KiB

    const int tid  = threadIdx.x;
    const int wid  = tid >> 6;        // 0..7
    const int lane = tid & 63;
    const int wr   = wid >> 2;        // 0..1 : 128-row slab
    const int wc   = wid & 3;         // 0..3 : 64-col slab
    const int lr   = lane & 15;
    const int g    = lane >> 4;       // k-chunk 0..3 within 64B k-half
    const int row0 = blockIdx.y * BM;
    const int col0 = blockIdx.x * BN;

    // Staging: half-tile = 256 rows x 64B = 1024 chunks of 16B; 2 per thread.
    // LDS dest linear in chunk index; global k-slot pre-swizzled (inverse):
    //   row = c>>2, s_l = c&3, s_g = (c&3) ^ ((c>>3)&3)   [(r>>1)&3 = (c>>3)&3]
    const int c0 = wid * 64 + lane;   // 0..511
    const int c1 = 512 + c0;          // 512..1023
    const int s0 = (((c0 & 3) ^ ((c0 >> 3) & 3))) * 16;
    const int s1 = (((c1 & 3) ^ ((c1 >> 3) & 3))) * 16;
    const int r0 = c0 >> 2;
    const int r1 = c1 >> 2;

    const uint8_t* gA0 = xq + (size_t)(row0 + r0) * KDIM + s0;
    const uint8_t* gA1 = xq + (size_t)(row0 + r1) * KDIM + s1;
    const uint8_t* gB0 = wq + (size_t)(col0 + r0) * KDIM + s0;
    const uint8_t* gB1 = wq + (size_t)(col0 + r1) * KDIM + s1;

    const int sread = (g ^ ((lr >> 1) & 3)) * 16;   // swizzled read slot
    const int ra = wr * 128 + lr;                   // A fragment base row
    const int cb = wc * 64 + lr;                    // B fragment base col

#define STAGE_A(sd, kh, ko) do {                                  \
        uint8_t* _l = &As[sd][kh][0][0];                          \
        gload_lds16(gA0 + (ko) + (kh) * 64, _l + c0 * 16);        \
        gload_lds16(gA1 + (ko) + (kh) * 64, _l + c1 * 16);        \
    } while (0)
#define STAGE_B(sd, kh, ko) do {                                  \
        uint8_t* _l = &Bs[sd][kh][0][0];                          \
        gload_lds16(gB0 + (ko) + (kh) * 64, _l + c0 * 16);        \
        gload_lds16(gB1 + (ko) + (kh) * 64, _l + c1 * 16);        \
    } while (0)

    i32x4 acc[8][4];
#pragma unroll
    for (int m = 0; m < 8; ++m)
#pragma unroll
        for (int n = 0; n < 4; ++n) acc[m][n] = (i32x4){0, 0, 0, 0};

    // Prologue: stage tile 0 (issue order A0,B0,A1,B1 = wait order).
    STAGE_A(0, 0, 0);
    STAGE_B(0, 0, 0);
    STAGE_A(0, 1, 0);
    STAGE_B(0, 1, 0);
    asm volatile("s_waitcnt vmcnt(4)" ::: "memory");   // A-kh0,B-kh0 landed
    __builtin_amdgcn_s_barrier();

#pragma unroll 1
    for (int t = 0; t < NT; ++t) {
        const int d  = t & 1;
        const int sd = d ^ 1;
        // Last tile re-stages its own sources (keeps vmcnt counts uniform;
        // lands in the dbuf that is no longer read -> harmless).
        const int ko = (t + 1 < NT ? t + 1 : t) * BKB;

        i32x4 a0[4], a1[4], b0[4], b1[4];

        // ---------------- phase 1: (mh=0, ks=0) ----------------
#pragma unroll
        for (int m = 0; m < 4; ++m)
            a0[m] = *(const i32x4*)&As[d][0][ra + m * 16][sread];
#pragma unroll
        for (int n = 0; n < 4; ++n)
            b0[n] = *(const i32x4*)&Bs[d][0][cb + n * 16][sread];
        STAGE_A(sd, 0, ko);
        __builtin_amdgcn_s_barrier();
        __builtin_amdgcn_s_setprio(1);
#pragma unroll
        for (int m = 0; m < 4; ++m)
#pragma unroll
            for (int n = 0; n < 4; ++n)
                acc[m][n] = __builtin_amdgcn_mfma_i32_16x16x64_i8(
                    a0[m], b0[n], acc[m][n], 0, 0, 0);
        __builtin_amdgcn_s_setprio(0);
        __builtin_amdgcn_s_barrier();

        // ---------------- phase 2: (mh=1, ks=0) ----------------
#pragma unroll
        for (int m = 0; m < 4; ++m)
            a1[m] = *(const i32x4*)&As[d][0][ra + 64 + m * 16][sread];
        STAGE_B(sd, 0, ko);
        asm volatile("s_waitcnt vmcnt(4)" ::: "memory");   // prev A1,B1 landed
        __builtin_amdgcn_s_barrier();
        __builtin_amdgcn_s_setprio(1);
#pragma unroll
        for (int m = 0; m < 4; ++m)
#pragma unroll
            for (int n = 0; n < 4; ++n)
                acc[4 + m][n] = __builtin_amdgcn_mfma_i32_16x16x64_i8(
                    a1[m], b0[n], acc[4 + m][n], 0, 0, 0);
        __builtin_amdgcn_s_setprio(0);
        __builtin_amdgcn_s_barrier();

        // ---------------- phase 3: (mh=0, ks=1) ----------------
#pragma unroll
        for (int m = 0; m < 4; ++m)
            a0[m] = *(const i32x4*)&As[d][1][ra + m * 16][sread];
#pragma unroll
        for (int n = 0; n < 4; ++n)
            b1[n] = *(const i32x4*)&Bs[d][1][cb + n * 16][sread];
        STAGE_A(sd, 1, ko);
        __builtin_amdgcn_s_barrier();
        __builtin_amdgcn_s_setprio(1);
#pragma unroll
        for (int m = 0; m < 4; ++m)
#pragma unroll
            for (int n = 0; n < 4; ++n)
                acc[m][n] = __builtin_amdgcn_mfma_i32_16x16x64_i8(
                    a0[m], b1[n], acc[m][n], 0, 0, 0);
        __builtin_amdgcn_s_setprio(0);
        __builtin_amdgcn_s_barrier();

        // ---------------- phase 4: (mh=1, ks=1) ----------------
#pragma unroll
        for (int m = 0; m < 4; ++m)
            a1[m] = *(const i32x4*)&As[d][1][ra + 64 + m * 16][sread];
        STAGE_B(sd, 1, ko);
        asm volatile("s_waitcnt vmcnt(4)" ::: "memory");   // this A0,B0 landed
        __builtin_amdgcn_s_barrier();
        __builtin_amdgcn_s_setprio(1);
#pragma unroll
        for (int m = 0; m < 4; ++m)
#pragma unroll
            for (int n = 0; n < 4; ++n)
                acc[4 + m][n] = __builtin_amdgcn_mfma_i32_16x16x64_i8(
                    a1[m], b1[n], acc[4 + m][n], 0, 0, 0);
        __builtin_amdgcn_s_setprio(0);
        __builtin_amdgcn_s_barrier();
    }
#undef STAGE_A
#undef STAGE_B

    // Epilogue. C/D layout (16x16): col = lane&15, row = (lane>>4)*4 + reg.
#pragma unroll
    for (int n = 0; n < 4; ++n) {
        const int col = col0 + wc * 64 + n * 16 + lr;
        const float bv = bias[col];
#pragma unroll
        for (int m = 0; m < 8; ++m) {
            const int rb = row0 + wr * 128 + m * 16 + g * 4;
#pragma unroll
            for (int r = 0; r < 4; ++r)
                out[(size_t)(rb + r) * NOUT + col] = (float)acc[m][n][r] + bv;
        }
    }
}

// ---------------------------------------------------------------------------
extern "C" void kernel_launch(void* const* d_in, const int* in_sizes, int n_in,
                              void* d_out, int out_size, void* d_ws, size_t ws_size,
                              hipStream_t stream) {
    const float* x = (const float*)d_in[0];   // [8192, 4096]
    const float* w = (const float*)d_in[1];   // [4096, 4096]
    const float* b = (const float*)d_in[2];   // [4096]
    float* out = (float*)d_out;               // [8192, 4096]

    // Workspace: xq 32 MiB + wq 16 MiB of i8 (+-1).
    uint8_t* xq = (uint8_t*)d_ws;
    uint8_t* wq = xq + (size_t)NROW * KDIM;
    (void)ws_size;

    const int n4x = NROW * KDIM / 4;
    const int n4t = n4x + NOUT * KDIM / 4;
    bin_i8_fused<<<3072, 256, 0, stream>>>(x, w, (uint32_t*)xq, (uint32_t*)wq,
                                           n4x, n4t);

    dim3 grid(NOUT / BN, NROW / BM);   // 16 x 32 = 512 blocks
    i8_mfma_gemm<<<grid, 512, 0, stream>>>(xq, wq, b, out);
}